// Round 3
// baseline (394.046 us; speedup 1.0000x reference)
//
#include <hip/hip_runtime.h>

#define N_ROWS  65536
#define D       1024
#define NB      512              // blocks in kernel 1 (2 per CU)
#define TPB     256
#define RPT     (N_ROWS / NB)    // 128 rows per thread, compile-time
#define K_NEIGH 64

// Kernel 1: per-column sum of squared differences vs the selected row.
// Thread t owns 4 consecutive columns (one float4); a block's 256 threads
// cover one full 1024-float row per step -> each wave reads 1 KiB
// contiguous (perfect coalescing). Block b processes rows b, b+NB, ...
// (RPT=128 rows, compile-time trip count for deep unroll/pipelining).
__global__ __launch_bounds__(TPB) void lm_colsumsq(
    const int* __restrict__ gid,
    const float* __restrict__ x,
    float* __restrict__ acc)
{
    const int t   = threadIdx.x;
    const int col = t << 2;
    const int g   = gid[0];

    const float4 sel = *reinterpret_cast<const float4*>(x + (size_t)g * D + col);

    float a0 = 0.f, a1 = 0.f, a2 = 0.f, a3 = 0.f;
    const float* p = x + (size_t)blockIdx.x * D + col;

    #pragma unroll 8
    for (int i = 0; i < RPT; ++i) {
        float4 v = *reinterpret_cast<const float4*>(p);
        p += (size_t)NB * D;
        float d0 = sel.x - v.x;
        float d1 = sel.y - v.y;
        float d2 = sel.z - v.z;
        float d3 = sel.w - v.w;
        a0 = fmaf(d0, d0, a0);
        a1 = fmaf(d1, d1, a1);
        a2 = fmaf(d2, d2, a2);
        a3 = fmaf(d3, d3, a3);
    }

    // NB adds per address (512), spread over 64 cachelines; device-scope.
    atomicAdd(&acc[col + 0], a0);
    atomicAdd(&acc[col + 1], a1);
    atomicAdd(&acc[col + 2], a2);
    atomicAdd(&acc[col + 3], a3);
}

// Kernel 2: bitonic-sort the 1024 squared sums ascending in LDS, then
// mean of sqrt of the 64 smallest (sqrt is monotone -> commutes with topk).
__global__ __launch_bounds__(D) void lm_topk(
    const float* __restrict__ acc,
    float* __restrict__ out)
{
    __shared__ float s[D];
    const int d = threadIdx.x;

    s[d] = acc[d];
    __syncthreads();

    for (int k = 2; k <= D; k <<= 1) {
        for (int j = k >> 1; j > 0; j >>= 1) {
            int ixj = d ^ j;
            if (ixj > d) {
                float a = s[d], b = s[ixj];
                bool asc = ((d & k) == 0);
                if ((a > b) == asc) { s[d] = b; s[ixj] = a; }
            }
            __syncthreads();
        }
    }

    if (d < K_NEIGH) {
        float v = sqrtf(s[d]);
        // threads 0..63 are exactly one 64-lane wave
        #pragma unroll
        for (int off = 32; off > 0; off >>= 1) v += __shfl_down(v, off);
        if (d == 0) out[0] = v * (1.0f / K_NEIGH);
    }
}

extern "C" void kernel_launch(void* const* d_in, const int* in_sizes, int n_in,
                              void* d_out, int out_size, void* d_ws, size_t ws_size,
                              hipStream_t stream)
{
    const int*   gid = (const int*)d_in[0];    // group_id (scalar int)
    const float* x   = (const float*)d_in[1];  // all_latents [N_ROWS * D] fp32
    float*       out = (float*)d_out;          // scalar fp32
    float*       acc = (float*)d_ws;           // D floats accumulator

    // d_ws is re-poisoned to 0xAA before every launch -> zero it (capture-safe)
    hipMemsetAsync(acc, 0, D * sizeof(float), stream);

    lm_colsumsq<<<NB, TPB, 0, stream>>>(gid, x, acc);
    lm_topk<<<1, D, 0, stream>>>(acc, out);
}